// Round 14
// baseline (131.933 us; speedup 1.0000x reference)
//
#include <hip/hip_runtime.h>
#include <math.h>

// ---------------------------------------------------------------------------
// HyperbolicInfoNCE on MI355X — Round 20: ZERO-ATOMIC gemm (plain partial
// stores), wide finalize.
//
// R19 post-mortem: occupancy lever conclusively dead (LDS 20KB, VGPR 52,
// occupancy STILL ~30%, dur 51). Wall pinned ~48.5us for every config with
// >=12 waves/CU. Last un-ablated suspect: in-loop global atomicAdds, whose
// acks sit in the vmcnt queue drained by every phase barrier. Contended L2
// RMW (16 blocks x 4 waves x same 64-address replica set) is the one
// mechanism that is (a) shared across waves at the barrier and (b)
// invariant to occupancy/LDS/barrier-count — the observed signature.
// R12/R16/R17 never tested a CLEAN zero-atomic variant.
//
// R20 = R14's structure with ALL gemm atomics removed:
//   row partials -> plain stores rp[16 chunks][8192]      (512KB, 1 writer/slot)
//   col partials -> per-wave LDS colAcc[4][512] (8KB, single-owner-lane
//     read-add-write, no atomics) -> end-of-kernel plain stores
//     cpart[64 strips][8192]                              (2MB, 1 writer/slot)
//   diag -> unchanged plain stores.
// finalize: 64 blocks x 256thr; rs[b]=sum16 rp, cs[b]=sum64 cpart (both
// coalesced), one atomicAdd(out)/block; out zeroed via hipMemsetAsync.
// convert: zeroing dropped (partials fully overwritten).
// Pre-committed split: gemm 36-42us => atomic-ack confirmed;
// gemm 47-50us => structural floor, declare it.
// ---------------------------------------------------------------------------

#define BDIM   8192
#define K_IN   129
#define K_PAD  160      // 5 * 32
#define BK     32
#define NKT    5        // k-tiles of 32
#define CTILES 8        // 64-col tiles per block (128 rows x 512 cols)
#define NCHUNK 16
#define NSTRIP 64

typedef __bf16  bf16x8 __attribute__((ext_vector_type(8)));
typedef float   f32x4  __attribute__((ext_vector_type(4)));
typedef unsigned short u16x4 __attribute__((ext_vector_type(4)));

// ws layout (bytes)
#define OFF_A     0u
#define OFF_B     (BDIM * K_PAD * 2u)                 // 2,621,440
#define OFF_RP    (2u * BDIM * K_PAD * 2u)            // rp[16][8192]  = 512KB
#define OFF_CPART (OFF_RP + NCHUNK * BDIM * 4u)       // cpart[64][8192] = 2MB
#define OFF_DG    (OFF_CPART + NSTRIP * BDIM * 4u)    // diag 32KB

// ---- hardware transcendentals (v_sqrt_f32 / v_log_f32 / v_exp_f32) ----
__device__ __forceinline__ float fast_sqrt(float x) {
#if __has_builtin(__builtin_amdgcn_sqrtf)
    return __builtin_amdgcn_sqrtf(x);
#else
    return sqrtf(x);
#endif
}
__device__ __forceinline__ float fast_log2(float x) {
#if __has_builtin(__builtin_amdgcn_logf)
    return __builtin_amdgcn_logf(x);       // log base 2
#else
    return __log2f(x);
#endif
}
__device__ __forceinline__ float fast_exp2(float x) {
#if __has_builtin(__builtin_amdgcn_exp2f)
    return __builtin_amdgcn_exp2f(x);      // 2^x
#else
    extern "C" __device__ float __ocml_native_exp2_f32(float);
    return __ocml_native_exp2_f32(x);
#endif
}

__device__ __forceinline__ unsigned short f2bf_rne(float f) {
    unsigned int u = __float_as_uint(f);
    u += 0x7FFFu + ((u >> 16) & 1u);   // round-to-nearest-even
    return (unsigned short)(u >> 16);
}

// ---------------------------------------------------------------------------
// Kernel 1: fp32 -> bf16, float4-granular. K zero-padded 129->160, Lorentz
// metric folded into A (negate col 0). No zeroing needed anymore.
// ---------------------------------------------------------------------------
__global__ __launch_bounds__(256) void convert_kernel(
    const float* __restrict__ z1, const float* __restrict__ z2,
    unsigned short* __restrict__ A, unsigned short* __restrict__ B)
{
    int v = blockIdx.x * 256 + threadIdx.x;
    if (v >= BDIM * (K_PAD / 4)) return;
    int r  = v / (K_PAD / 4);
    int c4 = (v - r * (K_PAD / 4)) * 4;
    u16x4 a, b;
    #pragma unroll
    for (int i = 0; i < 4; ++i) {
        int c = c4 + i;
        float va = 0.f, vb = 0.f;
        if (c < K_IN) {
            va = z1[r * K_IN + c];
            vb = z2[r * K_IN + c];
            if (c == 0) va = -va;              // Lorentz metric on coord 0
        }
        a[i] = f2bf_rne(va);
        b[i] = f2bf_rne(vb);
    }
    *(u16x4*)(A + r * K_PAD + c4) = a;
    *(u16x4*)(B + r * K_PAD + c4) = b;
}

// ---------------------------------------------------------------------------
// Kernel 2: strip-GEMM with fused acosh/exp epilogue; B staged through a
// double-buffered LDS pipeline (global_load_lds). ZERO global atomics.
//   grid = 1024: bid = chunk*64 + strip
//   block: rows [strip*128, +128) x cols [chunk*512, +512), 8 tiles of 64
//   wave w (0..3): rows [strip*128 + w*32, +32)
//   fragment layouts (guide-verified, m89/m91):
//     A/B operand: elem [m=lane&15][k=(lane>>4)*8 + j]
//     C/D:         elem [row=(lane>>4)*4 + reg][col=lane&15]
// ---------------------------------------------------------------------------

// Stage one 64-col B-tile (20KB contiguous global chunk) into Bs[bufidx].
// Each wave issues 5 async 1KB copies; LDS dest wave-uniform + lane*16 (m104).
#define STAGE(bufidx, cb)                                                     \
    {                                                                         \
        const char* _gp = (const char*)(B + (size_t)(cb) * K_PAD)             \
                          + wave * 5120 + lane * 16;                          \
        unsigned short* _lp = &Bs[bufidx][wave * 2560];                       \
        _Pragma("unroll")                                                     \
        for (int _i = 0; _i < 5; ++_i)                                        \
            __builtin_amdgcn_global_load_lds(                                 \
                (const __attribute__((address_space(1))) void*)               \
                    (_gp + _i * 1024),                                        \
                (__attribute__((address_space(3))) void*)(_lp + _i * 512),    \
                16, 0, 0);                                                    \
    }

// MFMA + fused epilogue for one 32x64 wave-tile read from Bs[bufidx].
// Col partials -> per-wave LDS slot (single-owner-lane +=, NO atomics).
#define COMPUTE(bufidx, cb)                                                   \
    {                                                                         \
        const int colBase = (cb);                                             \
        const unsigned short* _Bt = &Bs[bufidx][0];                           \
        f32x4 acc[2][4] = {};                                                 \
        _Pragma("unroll")                                                     \
        for (int kt = 0; kt < NKT; ++kt) {                                    \
            bf16x8 bfr[4];                                                    \
            _Pragma("unroll")                                                 \
            for (int j = 0; j < 4; ++j)                                       \
                bfr[j] = *(const bf16x8*)                                     \
                    &_Bt[(l16 + j * 16) * K_PAD + quad * 8 + kt * BK];        \
            _Pragma("unroll")                                                 \
            for (int i = 0; i < 2; ++i)                                       \
                _Pragma("unroll")                                             \
                for (int j = 0; j < 4; ++j)                                   \
                    acc[i][j] = __builtin_amdgcn_mfma_f32_16x16x32_bf16(      \
                        Ah[i][kt], bfr[j], acc[i][j], 0, 0, 0);               \
        }                                                                     \
        const bool diagTile = (colBase == (rowBase & ~63));                   \
        const int  dj       = (rowBase >> 4) & 2;                             \
        float colp[4] = {0.f, 0.f, 0.f, 0.f};                                 \
        _Pragma("unroll")                                                     \
        for (int i = 0; i < 2; ++i) {                                         \
            _Pragma("unroll")                                                 \
            for (int j = 0; j < 4; ++j) {                                     \
                _Pragma("unroll")                                             \
                for (int reg = 0; reg < 4; ++reg) {                           \
                    float inner = acc[i][j][reg];                             \
                    float x = fmaxf(-inner, 1.000001f);                       \
                    float s = fast_sqrt(__builtin_fmaf(x, x, -1.0f));         \
                    float l2u = fast_log2(x + s);                             \
                    float e = fast_exp2(-14.285714285714286f * l2u);          \
                    rowp[i][reg] += e;                                        \
                    colp[j]      += e;                                        \
                    if (diagTile && (j - i) == dj && (quad * 4 + reg) == l16){\
                        int R = rowBase + i * 16 + quad * 4 + reg;            \
                        diag[R] = -9.902102579427789f * l2u;                  \
                    }                                                         \
                }                                                             \
            }                                                                 \
        }                                                                     \
        _Pragma("unroll")                                                     \
        for (int j = 0; j < 4; ++j) {                                         \
            float v = colp[j];                                                \
            v += __shfl_xor(v, 16);                                           \
            v += __shfl_xor(v, 32);                                           \
            if (quad == 0) {                                                  \
                int _ci = wave * 512 + (colBase - colChunk) + j * 16 + l16;   \
                colAcc[_ci] += v;   /* single owner lane: plain LDS RMW */    \
            }                                                                 \
        }                                                                     \
    }

__global__ __launch_bounds__(256, 4) void gemm_epilogue_kernel(
    const unsigned short* __restrict__ A, const unsigned short* __restrict__ B,
    float* __restrict__ rp, float* __restrict__ cpart,
    float* __restrict__ diag)
{
    const int t    = threadIdx.x;
    const int lane = t & 63;
    const int wave = t >> 6;
    const int quad = lane >> 4;
    const int l16  = lane & 15;

    const int strip = blockIdx.x & 63;
    const int chunk = blockIdx.x >> 6;                // 0..15
    const int rowBase  = strip * 128 + wave * 32;     // wave's first row
    const int colChunk = chunk * 512;                 // block's first col

    const unsigned short* Abase = A + (rowBase + l16) * K_PAD + quad * 8;

    // B-tile double buffer (40,960B) + per-wave col accumulator (8,192B).
    __shared__ __align__(16) unsigned short Bs[2][64 * K_PAD];
    __shared__ float colAcc[4 * 512];

    #pragma unroll
    for (int c = t; c < 4 * 512; c += 256) colAcc[c] = 0.f;

    // ---- hoist the entire A operand for this wave: 2 row-frags x 5 k-tiles
    bf16x8 Ah[2][NKT];
    #pragma unroll
    for (int i = 0; i < 2; ++i)
        #pragma unroll
        for (int kt = 0; kt < NKT; ++kt)
            Ah[i][kt] = *(const bf16x8*)(Abase + i * 16 * K_PAD + kt * BK);

    float rowp[2][4] = {};   // persistent across all col-tiles

    // ---- 2-phase pipeline: stage next tile, compute current, one barrier
    STAGE(0, colChunk);                  // prologue: tile 0 -> Bs[0]
    __syncthreads();                     // also covers colAcc zeroing

    #pragma unroll 1
    for (int ct = 0; ct < CTILES; ++ct) {
        if (ct + 1 < CTILES)
            STAGE((ct + 1) & 1, colChunk + (ct + 1) * 64);
        COMPUTE(ct & 1, colChunk + ct * 64);
        __syncthreads();                 // drains ONLY stage loads (long done)
    }

    // ---- epilogue: plain partial stores, no atomics anywhere ----
    // row partials: reduce across the 16 lanes of each quad (they hold cols)
    #pragma unroll
    for (int i = 0; i < 2; ++i) {
        #pragma unroll
        for (int reg = 0; reg < 4; ++reg) {
            float v = rowp[i][reg];
            v += __shfl_xor(v, 1);
            v += __shfl_xor(v, 2);
            v += __shfl_xor(v, 4);
            v += __shfl_xor(v, 8);
            if (l16 == 0)
                rp[chunk * BDIM + rowBase + i * 16 + quad * 4 + reg] = v;
        }
    }
    // col partials: sum the 4 per-wave LDS rows, plain-store (1 writer/slot)
    __syncthreads();
    for (int c = t; c < 512; c += 256) {
        float s = colAcc[c] + colAcc[512 + c] + colAcc[1024 + c] +
                  colAcc[1536 + c];
        cpart[strip * BDIM + colChunk + c] = s;
    }
}

// ---------------------------------------------------------------------------
// Kernel 3: loss = mean_b( 0.5*(ln rs[b] + ln cs[b]) - diag[b] ).
// 64 blocks x 256thr; block handles rows [bid*128, +128); threads 0..127 own
// one row each. rs = sum of 16 chunk partials, cs = sum of 64 strip partials
// (both coalesced across threads). One atomicAdd(out) per block.
// ---------------------------------------------------------------------------
__global__ __launch_bounds__(256) void finalize_kernel(
    const float* __restrict__ rp, const float* __restrict__ cpart,
    const float* __restrict__ dg, float* __restrict__ out)
{
    __shared__ float part[2];
    int t = threadIdx.x;
    float a = 0.f;
    const float LN2_HALF = 0.34657359027997264f;  // 0.5 * ln2
    if (t < 128) {
        int b = blockIdx.x * 128 + t;
        float rs = 0.f, cs = 0.f;
        #pragma unroll
        for (int c = 0; c < NCHUNK; ++c) rs += rp[c * BDIM + b];
        #pragma unroll
        for (int s = 0; s < NSTRIP; ++s) cs += cpart[s * BDIM + b];
        a = LN2_HALF * (fast_log2(rs) + fast_log2(cs)) - dg[b];
    }
    #pragma unroll
    for (int m = 1; m < 64; m <<= 1) a += __shfl_xor(a, m);
    if ((t & 63) == 0 && t < 128) part[t >> 6] = a;
    __syncthreads();
    if (t == 0)
        atomicAdd(out, (part[0] + part[1]) * (1.0f / (float)BDIM));
}

// ---------------------------------------------------------------------------
extern "C" void kernel_launch(void* const* d_in, const int* in_sizes, int n_in,
                              void* d_out, int out_size, void* d_ws, size_t ws_size,
                              hipStream_t stream)
{
    const float* z1 = (const float*)d_in[0];
    const float* z2 = (const float*)d_in[1];
    float* out = (float*)d_out;

    char* ws = (char*)d_ws;
    unsigned short* A  = (unsigned short*)(ws + OFF_A);
    unsigned short* B  = (unsigned short*)(ws + OFF_B);
    float* rp          = (float*)(ws + OFF_RP);
    float* cpart       = (float*)(ws + OFF_CPART);
    float* diag        = (float*)(ws + OFF_DG);

    hipMemsetAsync(out, 0, sizeof(float), stream);

    convert_kernel<<<(BDIM * (K_PAD / 4) + 255) / 256, 256, 0, stream>>>(
        z1, z2, A, B);

    gemm_epilogue_kernel<<<1024, 256, 0, stream>>>(
        A, B, rp, cpart, diag);

    finalize_kernel<<<NSTRIP, 256, 0, stream>>>(rp, cpart, diag, out);
}

// Round 15
// 108.909 us; speedup vs baseline: 1.2114x; 1.2114x over previous
//
#include <hip/hip_runtime.h>
#include <math.h>

// ---------------------------------------------------------------------------
// HyperbolicInfoNCE on MI355X — Round 21: convoy de-phasing via per-block
// start stagger. Base = R14 (best, gemm 48.5us) verbatim + s_sleep stagger.
//
// R20 post-mortem: zero-atomic gemm REGRESSED (53.5us) — atomics triply
// exonerated. All structural suspects now refuted. Pipe arithmetic: trans
// 16cy/wave64 x 3.15M ops = 20.5us + 5us VALU = 25.6us issue floor (= the
// invariant VALUBusy*dur). No pipe saturated, yet SIMDs idle 47%.
// Decisive clue (R19): 4 INDEPENDENT blocks/SIMD, each ~55% VALU-hungry ->
// uncorrelated would give ~96% busy; measured 53%. Blocks are phase-LOCKED:
// identical code + simultaneous launch -> all do epilogue together (VALU
// queues), then stage/MFMA/barrier together (SIMDs idle). Duty 1920/3600
// = 53% = measured VALUBusy. No prior fix broke the TIME correlation.
//
// R21: block bid sleeps (bid%3) x ~1216cy (s_sleep 19/step) at entry.
// Round-robin dispatch: CU c hosts bids {c, c+256, c+512, c+768} whose
// residues mod 3 cover {0,1,2} -> every CU's co-resident blocks sit ~1/3
// phase apart -> some wave is always in its epilogue -> VALU stays fed.
// No inter-block sync exists to re-lock; stagger persists. Cost <=2.4Kcy.
// Pre-committed split: dur 30-36us => convoy confirmed; 47-50 => refuted
// and the kernel is at its expressible floor.
// ---------------------------------------------------------------------------

#define BDIM   8192
#define K_IN   129
#define K_PAD  160      // 5 * 32
#define BK     32
#define NKT    5        // k-tiles of 32
#define CTILES 8        // 64-col tiles per block (128 rows x 512 cols)

typedef __bf16  bf16x8 __attribute__((ext_vector_type(8)));
typedef float   f32x4  __attribute__((ext_vector_type(4)));
typedef unsigned short u16x4 __attribute__((ext_vector_type(4)));

// ws layout (bytes)
#define OFF_A    0u
#define OFF_B    (BDIM * K_PAD * 2u)                  // 2,621,440
#define OFF_RS   (2u * BDIM * K_PAD * 2u)             // 5,242,880
#define OFF_CP   (OFF_RS + BDIM * 4u)                 // 4 separated col replicas
#define OFF_DG   (OFF_CP + 4u * BDIM * 4u)

// ---- hardware transcendentals (v_sqrt_f32 / v_log_f32 / v_exp_f32) ----
__device__ __forceinline__ float fast_sqrt(float x) {
#if __has_builtin(__builtin_amdgcn_sqrtf)
    return __builtin_amdgcn_sqrtf(x);
#else
    return sqrtf(x);
#endif
}
__device__ __forceinline__ float fast_log2(float x) {
#if __has_builtin(__builtin_amdgcn_logf)
    return __builtin_amdgcn_logf(x);       // log base 2
#else
    return __log2f(x);
#endif
}
__device__ __forceinline__ float fast_exp2(float x) {
#if __has_builtin(__builtin_amdgcn_exp2f)
    return __builtin_amdgcn_exp2f(x);      // 2^x
#else
    extern "C" __device__ float __ocml_native_exp2_f32(float);
    return __ocml_native_exp2_f32(x);
#endif
}

__device__ __forceinline__ unsigned short f2bf_rne(float f) {
    unsigned int u = __float_as_uint(f);
    u += 0x7FFFu + ((u >> 16) & 1u);   // round-to-nearest-even
    return (unsigned short)(u >> 16);
}

// ---------------------------------------------------------------------------
// Kernel 1: fp32 -> bf16, float4-granular. K zero-padded 129->160, Lorentz
// metric folded into A (negate col 0). Also zeroes row_sum + 4 col replicas.
// ---------------------------------------------------------------------------
__global__ __launch_bounds__(256) void convert_kernel(
    const float* __restrict__ z1, const float* __restrict__ z2,
    unsigned short* __restrict__ A, unsigned short* __restrict__ B,
    float* __restrict__ rs_cp)
{
    int v = blockIdx.x * 256 + threadIdx.x;
    if (v < 5 * BDIM) rs_cp[v] = 0.f;          // rs (8192) + cp (4*8192)
    if (v >= BDIM * (K_PAD / 4)) return;
    int r  = v / (K_PAD / 4);
    int c4 = (v - r * (K_PAD / 4)) * 4;
    u16x4 a, b;
    #pragma unroll
    for (int i = 0; i < 4; ++i) {
        int c = c4 + i;
        float va = 0.f, vb = 0.f;
        if (c < K_IN) {
            va = z1[r * K_IN + c];
            vb = z2[r * K_IN + c];
            if (c == 0) va = -va;              // Lorentz metric on coord 0
        }
        a[i] = f2bf_rne(va);
        b[i] = f2bf_rne(vb);
    }
    *(u16x4*)(A + r * K_PAD + c4) = a;
    *(u16x4*)(B + r * K_PAD + c4) = b;
}

// ---------------------------------------------------------------------------
// Kernel 2: strip-GEMM with fused acosh/exp epilogue; B staged through a
// double-buffered LDS pipeline (global_load_lds). R14 structure + stagger.
//   grid = 1024: bid = chunk*64 + strip  (consecutive blocks share B-chunk)
//   block: rows [strip*128, +128) x cols [chunk*512, +512), 8 tiles of 64
//   wave w (0..3): rows [strip*128 + w*32, +32)
//   fragment layouts (guide-verified, m89/m91):
//     A/B operand: elem [m=lane&15][k=(lane>>4)*8 + j]
//     C/D:         elem [row=(lane>>4)*4 + reg][col=lane&15]
// ---------------------------------------------------------------------------

// Stage one 64-col B-tile (20KB contiguous global chunk) into Bs[bufidx].
// Each wave issues 5 async 1KB copies; LDS dest wave-uniform + lane*16 (m104).
#define STAGE(bufidx, cb)                                                     \
    {                                                                         \
        const char* _gp = (const char*)(B + (size_t)(cb) * K_PAD)             \
                          + wave * 5120 + lane * 16;                          \
        unsigned short* _lp = &Bs[bufidx][wave * 2560];                       \
        _Pragma("unroll")                                                     \
        for (int _i = 0; _i < 5; ++_i)                                        \
            __builtin_amdgcn_global_load_lds(                                 \
                (const __attribute__((address_space(1))) void*)               \
                    (_gp + _i * 1024),                                        \
                (__attribute__((address_space(3))) void*)(_lp + _i * 512),    \
                16, 0, 0);                                                    \
    }

// MFMA + fused epilogue for one 32x64 wave-tile read from Bs[bufidx].
#define COMPUTE(bufidx, cb)                                                   \
    {                                                                         \
        const int colBase = (cb);                                             \
        const unsigned short* _Bt = &Bs[bufidx][0];                           \
        f32x4 acc[2][4] = {};                                                 \
        _Pragma("unroll")                                                     \
        for (int kt = 0; kt < NKT; ++kt) {                                    \
            bf16x8 bfr[4];                                                    \
            _Pragma("unroll")                                                 \
            for (int j = 0; j < 4; ++j)                                       \
                bfr[j] = *(const bf16x8*)                                     \
                    &_Bt[(l16 + j * 16) * K_PAD + quad * 8 + kt * BK];        \
            _Pragma("unroll")                                                 \
            for (int i = 0; i < 2; ++i)                                       \
                _Pragma("unroll")                                             \
                for (int j = 0; j < 4; ++j)                                   \
                    acc[i][j] = __builtin_amdgcn_mfma_f32_16x16x32_bf16(      \
                        Ah[i][kt], bfr[j], acc[i][j], 0, 0, 0);               \
        }                                                                     \
        const bool diagTile = (colBase == (rowBase & ~63));                   \
        const int  dj       = (rowBase >> 4) & 2;                             \
        float colp[4] = {0.f, 0.f, 0.f, 0.f};                                 \
        _Pragma("unroll")                                                     \
        for (int i = 0; i < 2; ++i) {                                         \
            _Pragma("unroll")                                                 \
            for (int j = 0; j < 4; ++j) {                                     \
                _Pragma("unroll")                                             \
                for (int reg = 0; reg < 4; ++reg) {                           \
                    float inner = acc[i][j][reg];                             \
                    float x = fmaxf(-inner, 1.000001f);                       \
                    float s = fast_sqrt(__builtin_fmaf(x, x, -1.0f));         \
                    float l2u = fast_log2(x + s);                             \
                    float e = fast_exp2(-14.285714285714286f * l2u);          \
                    rowp[i][reg] += e;                                        \
                    colp[j]      += e;                                        \
                    if (diagTile && (j - i) == dj && (quad * 4 + reg) == l16){\
                        int R = rowBase + i * 16 + quad * 4 + reg;            \
                        diag[R] = -9.902102579427789f * l2u;                  \
                    }                                                         \
                }                                                             \
            }                                                                 \
        }                                                                     \
        _Pragma("unroll")                                                     \
        for (int j = 0; j < 4; ++j) {                                         \
            float v = colp[j];                                                \
            v += __shfl_xor(v, 16);                                           \
            v += __shfl_xor(v, 32);                                           \
            if (quad == 0)                                                    \
                atomicAdd(&colRep[colBase + j * 16 + l16], v);                \
        }                                                                     \
    }

__global__ __launch_bounds__(256, 4) void gemm_epilogue_kernel(
    const unsigned short* __restrict__ A, const unsigned short* __restrict__ B,
    float* __restrict__ row_sum, float* __restrict__ col_part,
    float* __restrict__ diag)
{
    const int t    = threadIdx.x;
    const int lane = t & 63;
    const int wave = t >> 6;
    const int quad = lane >> 4;
    const int l16  = lane & 15;

    // ---- convoy de-phasing: stagger block start by (bid%3) x ~1216 cy ----
    // (s_sleep arg must be a literal; loop with runtime trip count)
    {
        const int ph = blockIdx.x % 3;
        #pragma unroll 1
        for (int i = 0; i < ph; ++i) __builtin_amdgcn_s_sleep(19);
    }

    const int strip = blockIdx.x & 63;
    const int chunk = blockIdx.x >> 6;                // 0..15
    const int rowBase  = strip * 128 + wave * 32;     // wave's first row
    const int colChunk = chunk * 512;                 // block's first col

    const unsigned short* Abase = A + (rowBase + l16) * K_PAD + quad * 8;
    float* colRep = col_part + (strip & 3) * BDIM;    // contention / 4

    // B-tile double buffer: 40,960B.
    __shared__ __align__(16) unsigned short Bs[2][64 * K_PAD];

    // ---- hoist the entire A operand for this wave: 2 row-frags x 5 k-tiles
    bf16x8 Ah[2][NKT];
    #pragma unroll
    for (int i = 0; i < 2; ++i)
        #pragma unroll
        for (int kt = 0; kt < NKT; ++kt)
            Ah[i][kt] = *(const bf16x8*)(Abase + i * 16 * K_PAD + kt * BK);

    float rowp[2][4] = {};   // persistent across all col-tiles

    // ---- 2-phase pipeline: stage next tile, compute current, one barrier
    STAGE(0, colChunk);                  // prologue: tile 0 -> Bs[0]
    __syncthreads();

    #pragma unroll 1
    for (int ct = 0; ct < CTILES; ++ct) {
        if (ct + 1 < CTILES)
            STAGE((ct + 1) & 1, colChunk + (ct + 1) * 64);
        COMPUTE(ct & 1, colChunk + ct * 64);
        __syncthreads();                 // drains stage loads (done under compute)
    }

    // row sums: accumulated over all 8 col-tiles; reduce across the 16
    // lanes of each quad (they hold the cols), one atomic per row
    #pragma unroll
    for (int i = 0; i < 2; ++i) {
        #pragma unroll
        for (int reg = 0; reg < 4; ++reg) {
            float v = rowp[i][reg];
            v += __shfl_xor(v, 1);
            v += __shfl_xor(v, 2);
            v += __shfl_xor(v, 4);
            v += __shfl_xor(v, 8);
            if (l16 == 0)
                atomicAdd(&row_sum[rowBase + i * 16 + quad * 4 + reg], v);
        }
    }
}

// ---------------------------------------------------------------------------
// Kernel 3: loss = mean_b( 0.5*(ln rs[b] + ln cs[b]) - diag[b] ),
// cs[b] = sum of 4 separated replicas.
// ---------------------------------------------------------------------------
__global__ __launch_bounds__(1024) void finalize_kernel(
    const float* __restrict__ rs, const float* __restrict__ cp,
    const float* __restrict__ dg, float* __restrict__ out)
{
    __shared__ float part[16];
    int t = threadIdx.x;
    float a = 0.f;
    const float LN2_HALF = 0.34657359027997264f;  // 0.5 * ln2
    for (int b = t; b < BDIM; b += 1024) {
        float cs = cp[b] + cp[b + BDIM] + cp[b + 2 * BDIM] + cp[b + 3 * BDIM];
        a += LN2_HALF * (fast_log2(rs[b]) + fast_log2(cs)) - dg[b];
    }
    #pragma unroll
    for (int m = 1; m < 64; m <<= 1) a += __shfl_xor(a, m);
    if ((t & 63) == 0) part[t >> 6] = a;
    __syncthreads();
    if (t < 16) {
        float v = part[t];
        #pragma unroll
        for (int m = 1; m < 16; m <<= 1) v += __shfl_xor(v, m);
        if (t == 0) out[0] = v * (1.0f / (float)BDIM);
    }
}

// ---------------------------------------------------------------------------
extern "C" void kernel_launch(void* const* d_in, const int* in_sizes, int n_in,
                              void* d_out, int out_size, void* d_ws, size_t ws_size,
                              hipStream_t stream)
{
    const float* z1 = (const float*)d_in[0];
    const float* z2 = (const float*)d_in[1];
    float* out = (float*)d_out;

    char* ws = (char*)d_ws;
    unsigned short* A  = (unsigned short*)(ws + OFF_A);
    unsigned short* B  = (unsigned short*)(ws + OFF_B);
    float* row_sum     = (float*)(ws + OFF_RS);
    float* col_part    = (float*)(ws + OFF_CP);
    float* diag        = (float*)(ws + OFF_DG);

    convert_kernel<<<(BDIM * (K_PAD / 4) + 255) / 256, 256, 0, stream>>>(
        z1, z2, A, B, row_sum /* rs + 4 separated col replicas contiguous */);

    gemm_epilogue_kernel<<<1024, 256, 0, stream>>>(
        A, B, row_sum, col_part, diag);

    finalize_kernel<<<1, 1024, 0, stream>>>(row_sum, col_part, diag, out);
}